// Round 1
// baseline (885.094 us; speedup 1.0000x reference)
//
#include <hip/hip_runtime.h>
#include <stdint.h>

// Problem constants
#define B_    8
#define T_    512
#define V_    2048
#define H_    4
#define NE_   768
#define D_    8192      // V_*H_  (inner dim of Mt GEMM, and v-row length)
#define PWROW 32768     // V_*H_*H_ (proj_w row length)

typedef __attribute__((ext_vector_type(8))) short bf16x8;
typedef __attribute__((ext_vector_type(4))) float f32x4;

__device__ __forceinline__ unsigned short f2bf(float f) {
  union { float f; unsigned int u; } c; c.f = f;
  unsigned int u = c.u;
  return (unsigned short)((u + 0x7FFFu + ((u >> 16) & 1u)) >> 16);
}

// ---------------------------------------------------------------------------
// Kernel 1: att[b][i][j*4+h] = softmax_j(cooc[t_i, t_j, h]) + eye  (bf16)
// One wave per (b,i) row. 4096 blocks x 64 threads.
// ---------------------------------------------------------------------------
__global__ __launch_bounds__(64) void softmax_k(
    const int* __restrict__ x, const float* __restrict__ cooc,
    unsigned short* __restrict__ att) {
  const int bi = blockIdx.x;
  const int b = bi >> 9, i = bi & (T_ - 1);
  const int lane = threadIdx.x;
  const int ti = x[b * T_ + i];
  const float* crow = cooc + (size_t)ti * D_;

  float w[8][4];
  #pragma unroll
  for (int r = 0; r < 8; ++r) {
    const int j = lane + r * 64;
    const int tj = x[b * T_ + j];
    const float4 v = *(const float4*)(crow + (size_t)tj * H_);
    w[r][0] = v.x; w[r][1] = v.y; w[r][2] = v.z; w[r][3] = v.w;
  }
  float m[4] = {-1e30f, -1e30f, -1e30f, -1e30f};
  #pragma unroll
  for (int r = 0; r < 8; ++r)
    #pragma unroll
    for (int h = 0; h < 4; ++h) m[h] = fmaxf(m[h], w[r][h]);
  #pragma unroll
  for (int off = 32; off > 0; off >>= 1)
    #pragma unroll
    for (int h = 0; h < 4; ++h) m[h] = fmaxf(m[h], __shfl_xor(m[h], off));
  float s[4] = {0.f, 0.f, 0.f, 0.f};
  #pragma unroll
  for (int r = 0; r < 8; ++r)
    #pragma unroll
    for (int h = 0; h < 4; ++h) { w[r][h] = __expf(w[r][h] - m[h]); s[h] += w[r][h]; }
  #pragma unroll
  for (int off = 32; off > 0; off >>= 1)
    #pragma unroll
    for (int h = 0; h < 4; ++h) s[h] += __shfl_xor(s[h], off);
  float inv[4];
  #pragma unroll
  for (int h = 0; h < 4; ++h) inv[h] = 1.f / s[h];

  unsigned short* arow = att + (size_t)(b * T_ + i) * (T_ * H_);
  #pragma unroll
  for (int r = 0; r < 8; ++r) {
    const int j = lane + r * 64;
    const float d = (j == i) ? 1.f : 0.f;
    ushort4 o;
    o.x = f2bf(w[r][0] * inv[0] + d);
    o.y = f2bf(w[r][1] * inv[1] + d);
    o.z = f2bf(w[r][2] * inv[2] + d);
    o.w = f2bf(w[r][3] * inv[3] + d);
    *(ushort4*)(arow + (size_t)j * H_) = o;
  }
}

// ---------------------------------------------------------------------------
// Kernel 2: MtT[e][t*4+h] = sum_d proj_w[e, h*8192+d] * cooc_flat[t, d]  (bf16)
// GEMM per h: M=768 (e), N=2048 (t), K=8192. BM=128, BN=64, BK=32.
// 4 waves (2x2), each wave 64x32 output, acc 4x2 of 16x16 frags.
// Register-staged fp32 -> bf16 into LDS.
// ---------------------------------------------------------------------------
__global__ __launch_bounds__(256) void gemm1_k(
    const float* __restrict__ pw, const float* __restrict__ cooc,
    unsigned short* __restrict__ mtT) {
  __shared__ unsigned short As[128 * 32];  // [e-row][k]
  __shared__ unsigned short Bs[64 * 32];   // [t-row][k]
  const int h  = blockIdx.z;
  const int e0 = blockIdx.x * 128;
  const int t0 = blockIdx.y * 64;
  const int tid  = threadIdx.x;
  const int lane = tid & 63, wave = tid >> 6;
  const int wr = wave >> 1, wc = wave & 1;
  const int fr = lane & 15, fq = lane >> 4;

  f32x4 acc[4][2];
  #pragma unroll
  for (int m = 0; m < 4; ++m)
    #pragma unroll
    for (int n = 0; n < 2; ++n) acc[m][n] = (f32x4){0.f, 0.f, 0.f, 0.f};

  const float* aB = pw + (size_t)e0 * PWROW + (size_t)h * D_;
  const float* bB = cooc + (size_t)t0 * D_;

  for (int k0 = 0; k0 < D_; k0 += 32) {
    __syncthreads();
    #pragma unroll
    for (int c = 0; c < 4; ++c) {      // A tile: 128x32, 4 float4 per thread
      const int fe = (c * 256 + tid) * 4;
      const int row = fe >> 5, k = fe & 31;
      const float4 v = *(const float4*)(aB + (size_t)row * PWROW + k0 + k);
      ushort4 o; o.x = f2bf(v.x); o.y = f2bf(v.y); o.z = f2bf(v.z); o.w = f2bf(v.w);
      *(ushort4*)&As[fe] = o;
    }
    #pragma unroll
    for (int c = 0; c < 2; ++c) {      // B tile: 64x32, 2 float4 per thread
      const int fe = (c * 256 + tid) * 4;
      const int row = fe >> 5, k = fe & 31;
      const float4 v = *(const float4*)(bB + (size_t)row * D_ + k0 + k);
      ushort4 o; o.x = f2bf(v.x); o.y = f2bf(v.y); o.z = f2bf(v.z); o.w = f2bf(v.w);
      *(ushort4*)&Bs[fe] = o;
    }
    __syncthreads();
    bf16x8 af[4], bf[2];
    #pragma unroll
    for (int m = 0; m < 4; ++m)
      af[m] = *(const bf16x8*)&As[(wr * 64 + m * 16 + fr) * 32 + fq * 8];
    #pragma unroll
    for (int n = 0; n < 2; ++n)
      bf[n] = *(const bf16x8*)&Bs[(wc * 32 + n * 16 + fr) * 32 + fq * 8];
    #pragma unroll
    for (int m = 0; m < 4; ++m)
      #pragma unroll
      for (int n = 0; n < 2; ++n)
        acc[m][n] = __builtin_amdgcn_mfma_f32_16x16x32_bf16(af[m], bf[n], acc[m][n], 0, 0, 0);
  }

  // Epilogue: D frag layout col=lane&15 (t), row=(lane>>4)*4+reg (e).
  #pragma unroll
  for (int m = 0; m < 4; ++m)
    #pragma unroll
    for (int n = 0; n < 2; ++n) {
      const int e = e0 + wr * 64 + m * 16 + fq * 4;
      const int t = t0 + wc * 32 + n * 16 + fr;
      #pragma unroll
      for (int r = 0; r < 4; ++r)
        mtT[(size_t)(e + r) * D_ + t * H_ + h] = f2bf(acc[m][n][r]);
    }
}

// ---------------------------------------------------------------------------
// Kernel 3: y[b][i][e] = sum_{j,h} att[b,i,(j,h)] * MtT[e][t_j*4+h] + pb[e]
// Per b: GEMM M=512 (i), N=768 (e), K=2048 ((j,h)). BM=64, BN=128, BK=32.
// B-tile gathered from MtT in 8-byte (4 x h) chunks using token ids.
// ---------------------------------------------------------------------------
__global__ __launch_bounds__(256) void gemm3_k(
    const unsigned short* __restrict__ att, const unsigned short* __restrict__ mtT,
    const int* __restrict__ x, const float* __restrict__ bias,
    float* __restrict__ y) {
  __shared__ unsigned short As[64 * 32];   // [i-row][k]
  __shared__ unsigned short Bs[128 * 32];  // [e-row][k]
  const int b  = blockIdx.z;
  const int i0 = blockIdx.x * 64;
  const int e0 = blockIdx.y * 128;
  const int tid  = threadIdx.x;
  const int lane = tid & 63, wave = tid >> 6;
  const int wr = wave >> 1, wc = wave & 1;
  const int fr = lane & 15, fq = lane >> 4;

  f32x4 acc[2][4];
  #pragma unroll
  for (int m = 0; m < 2; ++m)
    #pragma unroll
    for (int n = 0; n < 4; ++n) acc[m][n] = (f32x4){0.f, 0.f, 0.f, 0.f};

  const unsigned short* aB = att + (size_t)(b * T_ + i0) * (T_ * H_);

  for (int ks = 0; ks < 64; ++ks) {
    const int k0 = ks * 32;
    __syncthreads();
    {                                   // A tile: 64x32 bf16, one 16B chunk per thread
      const int fe = tid * 8;
      const int row = fe >> 5, k = fe & 31;
      const uint4 v = *(const uint4*)(aB + (size_t)row * (T_ * H_) + k0 + k);
      *(uint4*)&As[fe] = v;
    }
    #pragma unroll
    for (int c = 0; c < 4; ++c) {       // B tile: 128x32, gathered 8B chunks
      const int q = c * 256 + tid;
      const int n = q >> 3, j8 = q & 7;
      const int tj = x[b * T_ + ks * 8 + j8];
      const uint2 v = *(const uint2*)(mtT + (size_t)(e0 + n) * D_ + tj * H_);
      *(uint2*)&Bs[n * 32 + j8 * 4] = v;
    }
    __syncthreads();
    bf16x8 af[2], bf[4];
    #pragma unroll
    for (int m = 0; m < 2; ++m)
      af[m] = *(const bf16x8*)&As[(wr * 32 + m * 16 + fr) * 32 + fq * 8];
    #pragma unroll
    for (int n = 0; n < 4; ++n)
      bf[n] = *(const bf16x8*)&Bs[(wc * 64 + n * 16 + fr) * 32 + fq * 8];
    #pragma unroll
    for (int m = 0; m < 2; ++m)
      #pragma unroll
      for (int n = 0; n < 4; ++n)
        acc[m][n] = __builtin_amdgcn_mfma_f32_16x16x32_bf16(af[m], bf[n], acc[m][n], 0, 0, 0);
  }

  #pragma unroll
  for (int m = 0; m < 2; ++m)
    #pragma unroll
    for (int n = 0; n < 4; ++n) {
      const int i = i0 + wr * 32 + m * 16 + fq * 4;
      const int e = e0 + wc * 64 + n * 16 + fr;
      const float be = bias[e];
      #pragma unroll
      for (int r = 0; r < 4; ++r)
        y[(size_t)(b * T_ + i + r) * NE_ + e] = acc[m][n][r] + be;
    }
}

// ---------------------------------------------------------------------------
extern "C" void kernel_launch(void* const* d_in, const int* in_sizes, int n_in,
                              void* d_out, int out_size, void* d_ws, size_t ws_size,
                              hipStream_t stream) {
  const int*   x    = (const int*)d_in[0];
  const float* cooc = (const float*)d_in[1];
  const float* pw   = (const float*)d_in[2];
  const float* pb   = (const float*)d_in[3];
  float* y = (float*)d_out;

  // Workspace layout (bf16): MtT [768][8192] then att [8*512][2048]
  unsigned short* mtT = (unsigned short*)d_ws;
  unsigned short* att = mtT + (size_t)NE_ * D_;

  hipLaunchKernelGGL(gemm1_k, dim3(NE_ / 128, V_ / 64, H_), dim3(256), 0, stream,
                     pw, cooc, mtT);
  hipLaunchKernelGGL(softmax_k, dim3(B_ * T_), dim3(64), 0, stream, x, cooc, att);
  hipLaunchKernelGGL(gemm3_k, dim3(T_ / 64, NE_ / 128, B_), dim3(256), 0, stream,
                     att, mtT, x, pb, y);
}

// Round 2
// 529.809 us; speedup vs baseline: 1.6706x; 1.6706x over previous
//
#include <hip/hip_runtime.h>
#include <stdint.h>

// Problem constants
#define B_    8
#define T_    512
#define V_    2048
#define H_    4
#define NE_   768
#define D_    8192      // V_*H_  (inner dim of Mt GEMM, and v-row length)
#define PWROW 32768     // V_*H_*H_ (proj_w row length)
#define M1    3072      // NE_*H_  (rows of proj_w viewed as (3072, 8192))

typedef __attribute__((ext_vector_type(8))) short bf16x8;
typedef __attribute__((ext_vector_type(4))) float f32x4;

__device__ __forceinline__ unsigned short f2bf(float f) {
  union { float f; unsigned int u; } c; c.f = f;
  unsigned int u = c.u;
  return (unsigned short)((u + 0x7FFFu + ((u >> 16) & 1u)) >> 16);
}

// ---------------------------------------------------------------------------
// fp32 -> bf16 elementwise convert (vectorized, grid-stride)
// ---------------------------------------------------------------------------
__global__ __launch_bounds__(256) void cvt_k(
    const float* __restrict__ src, unsigned short* __restrict__ dst, int n4) {
  int i = blockIdx.x * 256 + threadIdx.x;
  const int stride = gridDim.x * 256;
  for (; i < n4; i += stride) {
    const float4 v = ((const float4*)src)[i];
    ushort4 o;
    o.x = f2bf(v.x); o.y = f2bf(v.y); o.z = f2bf(v.z); o.w = f2bf(v.w);
    ((ushort4*)dst)[i] = o;
  }
}

// ---------------------------------------------------------------------------
// Kernel 1 (fast): C[m][t] = sum_k Aq[m][k] * Bq[t][k], m=(e*4+h)
// M=3072, N=2048, K=8192 bf16. m97 structure: 128x128 tile, BK=32, 4 waves,
// 4x4 acc/wave, global_load_lds width-16 staging, single-buffered LDS.
// Output scattered as mtT[e][t*4+h] (bf16).
// ---------------------------------------------------------------------------
__global__ __launch_bounds__(256) void gemm1f_k(
    const unsigned short* __restrict__ Aq,   // [3072][8192]
    const unsigned short* __restrict__ Bq,   // [2048][8192]
    unsigned short* __restrict__ mtT) {      // [768][8192] as [e][t*4+h]
  __shared__ unsigned short As[128 * 32];
  __shared__ unsigned short Bs[128 * 32];
  const int r0 = blockIdx.x * 128;   // m
  const int t0 = blockIdx.y * 128;   // t
  const int tid  = threadIdx.x;
  const int lane = tid & 63, wave = tid >> 6;
  const int wr = wave >> 1, wc = wave & 1;
  const int fr = lane & 15, fq = lane >> 4;
  const int l4 = lane >> 2, lb = lane & 3;   // staging: row-in-chunk, 16B slot

  f32x4 acc[4][4];
  #pragma unroll
  for (int m = 0; m < 4; ++m)
    #pragma unroll
    for (int n = 0; n < 4; ++n) acc[m][n] = (f32x4){0.f, 0.f, 0.f, 0.f};

  for (int k0 = 0; k0 < D_; k0 += 32) {
    __syncthreads();
    #pragma unroll
    for (int c = 0; c < 2; ++c) {
      const int ch  = wave * 2 + c;          // 8 chunks of 16 rows each
      const int row = ch * 16 + l4;
      __builtin_amdgcn_global_load_lds(
          (const __attribute__((address_space(1))) void*)
              (Aq + (size_t)(r0 + row) * D_ + k0 + lb * 8),
          (__attribute__((address_space(3))) void*)(As + ch * 512),
          16, 0, 0);
      __builtin_amdgcn_global_load_lds(
          (const __attribute__((address_space(1))) void*)
              (Bq + (size_t)(t0 + row) * D_ + k0 + lb * 8),
          (__attribute__((address_space(3))) void*)(Bs + ch * 512),
          16, 0, 0);
    }
    __syncthreads();
    bf16x8 af[4], bf[4];
    #pragma unroll
    for (int m = 0; m < 4; ++m)
      af[m] = *(const bf16x8*)&As[(wr * 64 + m * 16 + fr) * 32 + fq * 8];
    #pragma unroll
    for (int n = 0; n < 4; ++n)
      bf[n] = *(const bf16x8*)&Bs[(wc * 64 + n * 16 + fr) * 32 + fq * 8];
    #pragma unroll
    for (int m = 0; m < 4; ++m)
      #pragma unroll
      for (int n = 0; n < 4; ++n)
        acc[m][n] = __builtin_amdgcn_mfma_f32_16x16x32_bf16(af[m], bf[n], acc[m][n], 0, 0, 0);
  }

  // Epilogue: C row = m-index (e*4+h), col = t. frag: col=lane&15, row=fq*4+reg.
  #pragma unroll
  for (int m = 0; m < 4; ++m)
    #pragma unroll
    for (int n = 0; n < 4; ++n) {
      const int r = r0 + wr * 64 + m * 16 + fq * 4;
      const int t = t0 + wc * 64 + n * 16 + fr;
      #pragma unroll
      for (int g = 0; g < 4; ++g) {
        const int rr = r + g;
        mtT[(size_t)(rr >> 2) * D_ + t * H_ + (rr & 3)] = f2bf(acc[m][n][g]);
      }
    }
}

// ---------------------------------------------------------------------------
// Kernel 1 (fallback, round-1 version): fp32 reg-staged, used if ws too small
// ---------------------------------------------------------------------------
__global__ __launch_bounds__(256) void gemm1_k(
    const float* __restrict__ pw, const float* __restrict__ cooc,
    unsigned short* __restrict__ mtT) {
  __shared__ unsigned short As[128 * 32];
  __shared__ unsigned short Bs[64 * 32];
  const int h  = blockIdx.z;
  const int e0 = blockIdx.x * 128;
  const int t0 = blockIdx.y * 64;
  const int tid  = threadIdx.x;
  const int lane = tid & 63, wave = tid >> 6;
  const int wr = wave >> 1, wc = wave & 1;
  const int fr = lane & 15, fq = lane >> 4;

  f32x4 acc[4][2];
  #pragma unroll
  for (int m = 0; m < 4; ++m)
    #pragma unroll
    for (int n = 0; n < 2; ++n) acc[m][n] = (f32x4){0.f, 0.f, 0.f, 0.f};

  const float* aB = pw + (size_t)e0 * PWROW + (size_t)h * D_;
  const float* bB = cooc + (size_t)t0 * D_;

  for (int k0 = 0; k0 < D_; k0 += 32) {
    __syncthreads();
    #pragma unroll
    for (int c = 0; c < 4; ++c) {
      const int fe = (c * 256 + tid) * 4;
      const int row = fe >> 5, k = fe & 31;
      const float4 v = *(const float4*)(aB + (size_t)row * PWROW + k0 + k);
      ushort4 o; o.x = f2bf(v.x); o.y = f2bf(v.y); o.z = f2bf(v.z); o.w = f2bf(v.w);
      *(ushort4*)&As[fe] = o;
    }
    #pragma unroll
    for (int c = 0; c < 2; ++c) {
      const int fe = (c * 256 + tid) * 4;
      const int row = fe >> 5, k = fe & 31;
      const float4 v = *(const float4*)(bB + (size_t)row * D_ + k0 + k);
      ushort4 o; o.x = f2bf(v.x); o.y = f2bf(v.y); o.z = f2bf(v.z); o.w = f2bf(v.w);
      *(ushort4*)&Bs[fe] = o;
    }
    __syncthreads();
    bf16x8 af[4], bf[2];
    #pragma unroll
    for (int m = 0; m < 4; ++m)
      af[m] = *(const bf16x8*)&As[(wr * 64 + m * 16 + fr) * 32 + fq * 8];
    #pragma unroll
    for (int n = 0; n < 2; ++n)
      bf[n] = *(const bf16x8*)&Bs[(wc * 32 + n * 16 + fr) * 32 + fq * 8];
    #pragma unroll
    for (int m = 0; m < 4; ++m)
      #pragma unroll
      for (int n = 0; n < 2; ++n)
        acc[m][n] = __builtin_amdgcn_mfma_f32_16x16x32_bf16(af[m], bf[n], acc[m][n], 0, 0, 0);
  }

  #pragma unroll
  for (int m = 0; m < 4; ++m)
    #pragma unroll
    for (int n = 0; n < 2; ++n) {
      const int e = e0 + wr * 64 + m * 16 + fq * 4;
      const int t = t0 + wc * 32 + n * 16 + fr;
      #pragma unroll
      for (int g = 0; g < 4; ++g)
        mtT[(size_t)(e + g) * D_ + t * H_ + h] = f2bf(acc[m][n][g]);
    }
}

// ---------------------------------------------------------------------------
// Kernel 2: att[b][i][j*4+h] = softmax_j(cooc[t_i, t_j, h]) + eye  (bf16)
// ---------------------------------------------------------------------------
__global__ __launch_bounds__(64) void softmax_k(
    const int* __restrict__ x, const float* __restrict__ cooc,
    unsigned short* __restrict__ att) {
  const int bi = blockIdx.x;
  const int b = bi >> 9, i = bi & (T_ - 1);
  const int lane = threadIdx.x;
  const int ti = x[b * T_ + i];
  const float* crow = cooc + (size_t)ti * D_;

  float w[8][4];
  #pragma unroll
  for (int r = 0; r < 8; ++r) {
    const int j = lane + r * 64;
    const int tj = x[b * T_ + j];
    const float4 v = *(const float4*)(crow + (size_t)tj * H_);
    w[r][0] = v.x; w[r][1] = v.y; w[r][2] = v.z; w[r][3] = v.w;
  }
  float m[4] = {-1e30f, -1e30f, -1e30f, -1e30f};
  #pragma unroll
  for (int r = 0; r < 8; ++r)
    #pragma unroll
    for (int h = 0; h < 4; ++h) m[h] = fmaxf(m[h], w[r][h]);
  #pragma unroll
  for (int off = 32; off > 0; off >>= 1)
    #pragma unroll
    for (int h = 0; h < 4; ++h) m[h] = fmaxf(m[h], __shfl_xor(m[h], off));
  float s[4] = {0.f, 0.f, 0.f, 0.f};
  #pragma unroll
  for (int r = 0; r < 8; ++r)
    #pragma unroll
    for (int h = 0; h < 4; ++h) { w[r][h] = __expf(w[r][h] - m[h]); s[h] += w[r][h]; }
  #pragma unroll
  for (int off = 32; off > 0; off >>= 1)
    #pragma unroll
    for (int h = 0; h < 4; ++h) s[h] += __shfl_xor(s[h], off);
  float inv[4];
  #pragma unroll
  for (int h = 0; h < 4; ++h) inv[h] = 1.f / s[h];

  unsigned short* arow = att + (size_t)(b * T_ + i) * (T_ * H_);
  #pragma unroll
  for (int r = 0; r < 8; ++r) {
    const int j = lane + r * 64;
    const float d = (j == i) ? 1.f : 0.f;
    ushort4 o;
    o.x = f2bf(w[r][0] * inv[0] + d);
    o.y = f2bf(w[r][1] * inv[1] + d);
    o.z = f2bf(w[r][2] * inv[2] + d);
    o.w = f2bf(w[r][3] * inv[3] + d);
    *(ushort4*)(arow + (size_t)j * H_) = o;
  }
}

// ---------------------------------------------------------------------------
// Kernel 3: y[b][i][e] = sum_{j,h} att[b,i,(j,h)] * MtT[e][t_j*4+h] + pb[e]
// ---------------------------------------------------------------------------
__global__ __launch_bounds__(256) void gemm3_k(
    const unsigned short* __restrict__ att, const unsigned short* __restrict__ mtT,
    const int* __restrict__ x, const float* __restrict__ bias,
    float* __restrict__ y) {
  __shared__ unsigned short As[64 * 32];   // [i-row][k]
  __shared__ unsigned short Bs[128 * 32];  // [e-row][k]
  const int b  = blockIdx.z;
  const int i0 = blockIdx.x * 64;
  const int e0 = blockIdx.y * 128;
  const int tid  = threadIdx.x;
  const int lane = tid & 63, wave = tid >> 6;
  const int wr = wave >> 1, wc = wave & 1;
  const int fr = lane & 15, fq = lane >> 4;

  f32x4 acc[2][4];
  #pragma unroll
  for (int m = 0; m < 2; ++m)
    #pragma unroll
    for (int n = 0; n < 4; ++n) acc[m][n] = (f32x4){0.f, 0.f, 0.f, 0.f};

  const unsigned short* aB = att + (size_t)(b * T_ + i0) * (T_ * H_);

  for (int ks = 0; ks < 64; ++ks) {
    const int k0 = ks * 32;
    __syncthreads();
    {
      const int fe = tid * 8;
      const int row = fe >> 5, k = fe & 31;
      const uint4 v = *(const uint4*)(aB + (size_t)row * (T_ * H_) + k0 + k);
      *(uint4*)&As[fe] = v;
    }
    #pragma unroll
    for (int c = 0; c < 4; ++c) {
      const int q = c * 256 + tid;
      const int n = q >> 3, j8 = q & 7;
      const int tj = x[b * T_ + ks * 8 + j8];
      const uint2 v = *(const uint2*)(mtT + (size_t)(e0 + n) * D_ + tj * H_);
      *(uint2*)&Bs[n * 32 + j8 * 4] = v;
    }
    __syncthreads();
    bf16x8 af[2], bf[4];
    #pragma unroll
    for (int m = 0; m < 2; ++m)
      af[m] = *(const bf16x8*)&As[(wr * 32 + m * 16 + fr) * 32 + fq * 8];
    #pragma unroll
    for (int n = 0; n < 4; ++n)
      bf[n] = *(const bf16x8*)&Bs[(wc * 64 + n * 16 + fr) * 32 + fq * 8];
    #pragma unroll
    for (int m = 0; m < 2; ++m)
      #pragma unroll
      for (int n = 0; n < 4; ++n)
        acc[m][n] = __builtin_amdgcn_mfma_f32_16x16x32_bf16(af[m], bf[n], acc[m][n], 0, 0, 0);
  }

  #pragma unroll
  for (int m = 0; m < 2; ++m)
    #pragma unroll
    for (int n = 0; n < 4; ++n) {
      const int i = i0 + wr * 32 + m * 16 + fq * 4;
      const int e = e0 + wc * 64 + n * 16 + fr;
      const float be = bias[e];
      #pragma unroll
      for (int g = 0; g < 4; ++g)
        y[(size_t)(b * T_ + i + g) * NE_ + e] = acc[m][n][g] + be;
    }
}

// ---------------------------------------------------------------------------
extern "C" void kernel_launch(void* const* d_in, const int* in_sizes, int n_in,
                              void* d_out, int out_size, void* d_ws, size_t ws_size,
                              hipStream_t stream) {
  const int*   x    = (const int*)d_in[0];
  const float* cooc = (const float*)d_in[1];
  const float* pw   = (const float*)d_in[2];
  const float* pb   = (const float*)d_in[3];
  float* y = (float*)d_out;

  // Fast-path ws layout (ushort elems): [mtT 6291456][Bq 16777216][Aq 25165824]
  // att (8388608 elems) aliases into Aq after gemm1f completes.
  const size_t MTT_E = (size_t)NE_ * D_;          // 6291456
  const size_t BQ_E  = (size_t)V_ * D_;           // 16777216
  const size_t AQ_E  = (size_t)M1 * D_;           // 25165824
  const size_t need_fast = (MTT_E + BQ_E + AQ_E) * 2;  // 96.5 MB

  unsigned short* mtT = (unsigned short*)d_ws;

  if (ws_size >= need_fast) {
    unsigned short* Bq  = mtT + MTT_E;
    unsigned short* Aq  = Bq + BQ_E;
    unsigned short* att = Aq;   // alias: valid after gemm1f
    hipLaunchKernelGGL(cvt_k, dim3(2048), dim3(256), 0, stream,
                       pw, Aq, (int)(AQ_E / 4));
    hipLaunchKernelGGL(cvt_k, dim3(2048), dim3(256), 0, stream,
                       cooc, Bq, (int)(BQ_E / 4));
    hipLaunchKernelGGL(gemm1f_k, dim3(M1 / 128, V_ / 128), dim3(256), 0, stream,
                       Aq, Bq, mtT);
    hipLaunchKernelGGL(softmax_k, dim3(B_ * T_), dim3(64), 0, stream, x, cooc, att);
    hipLaunchKernelGGL(gemm3_k, dim3(T_ / 64, NE_ / 128, B_), dim3(256), 0, stream,
                       att, mtT, x, pb, y);
  } else {
    // Fallback: round-1 path (29.4 MB ws)
    unsigned short* att = mtT + MTT_E;
    hipLaunchKernelGGL(gemm1_k, dim3(NE_ / 128, V_ / 64, H_), dim3(256), 0, stream,
                       pw, cooc, mtT);
    hipLaunchKernelGGL(softmax_k, dim3(B_ * T_), dim3(64), 0, stream, x, cooc, att);
    hipLaunchKernelGGL(gemm3_k, dim3(T_ / 64, NE_ / 128, B_), dim3(256), 0, stream,
                       att, mtT, x, pb, y);
  }
}

// Round 3
// 277.514 us; speedup vs baseline: 3.1894x; 1.9091x over previous
//
#include <hip/hip_runtime.h>
#include <stdint.h>

// Problem constants
#define B_    8
#define T_    512
#define V_    2048
#define H_    4
#define NE_   768
#define D_    8192      // V_*H_  (inner dim of Mt GEMM, and v-row length)
#define PWROW 32768     // V_*H_*H_ (proj_w row length)
#define M1    3072      // NE_*H_  (rows of proj_w viewed as (3072, 8192))
#define K3    2048      // T_*H_   (inner dim of gemm3)

typedef __attribute__((ext_vector_type(8))) short bf16x8;
typedef __attribute__((ext_vector_type(4))) float f32x4;

__device__ __forceinline__ unsigned short f2bf(float f) {
  union { float f; unsigned int u; } c; c.f = f;
  unsigned int u = c.u;
  return (unsigned short)((u + 0x7FFFu + ((u >> 16) & 1u)) >> 16);
}

// ---------------------------------------------------------------------------
// fp32 -> bf16 elementwise convert (vectorized, grid-stride)
// ---------------------------------------------------------------------------
__global__ __launch_bounds__(256) void cvt_k(
    const float* __restrict__ src, unsigned short* __restrict__ dst, int n4) {
  int i = blockIdx.x * 256 + threadIdx.x;
  const int stride = gridDim.x * 256;
  for (; i < n4; i += stride) {
    const float4 v = ((const float4*)src)[i];
    ushort4 o;
    o.x = f2bf(v.x); o.y = f2bf(v.y); o.z = f2bf(v.z); o.w = f2bf(v.w);
    ((ushort4*)dst)[i] = o;
  }
}

// ---------------------------------------------------------------------------
// Kernel 1 (fast): C[m][t] = sum_k Aq[m][k] * Bq[t][k], m=(e*4+h)
// M=3072, N=2048, K=8192 bf16. m97 structure: 128x128 tile, BK=32, 4 waves,
// 4x4 acc/wave, global_load_lds width-16 staging, single-buffered LDS.
// Output scattered as mtT[e][t*4+h] (bf16).
// ---------------------------------------------------------------------------
__global__ __launch_bounds__(256) void gemm1f_k(
    const unsigned short* __restrict__ Aq,   // [3072][8192]
    const unsigned short* __restrict__ Bq,   // [2048][8192]
    unsigned short* __restrict__ mtT) {      // [768][8192] as [e][t*4+h]
  __shared__ unsigned short As[128 * 32];
  __shared__ unsigned short Bs[128 * 32];
  const int r0 = blockIdx.x * 128;   // m
  const int t0 = blockIdx.y * 128;   // t
  const int tid  = threadIdx.x;
  const int lane = tid & 63, wave = tid >> 6;
  const int wr = wave >> 1, wc = wave & 1;
  const int fr = lane & 15, fq = lane >> 4;
  const int l4 = lane >> 2, lb = lane & 3;   // staging: row-in-chunk, 16B slot

  f32x4 acc[4][4];
  #pragma unroll
  for (int m = 0; m < 4; ++m)
    #pragma unroll
    for (int n = 0; n < 4; ++n) acc[m][n] = (f32x4){0.f, 0.f, 0.f, 0.f};

  for (int k0 = 0; k0 < D_; k0 += 32) {
    __syncthreads();
    #pragma unroll
    for (int c = 0; c < 2; ++c) {
      const int ch  = wave * 2 + c;          // 8 chunks of 16 rows each
      const int row = ch * 16 + l4;
      __builtin_amdgcn_global_load_lds(
          (const __attribute__((address_space(1))) void*)
              (Aq + (size_t)(r0 + row) * D_ + k0 + lb * 8),
          (__attribute__((address_space(3))) void*)(As + ch * 512),
          16, 0, 0);
      __builtin_amdgcn_global_load_lds(
          (const __attribute__((address_space(1))) void*)
              (Bq + (size_t)(t0 + row) * D_ + k0 + lb * 8),
          (__attribute__((address_space(3))) void*)(Bs + ch * 512),
          16, 0, 0);
    }
    __syncthreads();
    bf16x8 af[4], bf[4];
    #pragma unroll
    for (int m = 0; m < 4; ++m)
      af[m] = *(const bf16x8*)&As[(wr * 64 + m * 16 + fr) * 32 + fq * 8];
    #pragma unroll
    for (int n = 0; n < 4; ++n)
      bf[n] = *(const bf16x8*)&Bs[(wc * 64 + n * 16 + fr) * 32 + fq * 8];
    #pragma unroll
    for (int m = 0; m < 4; ++m)
      #pragma unroll
      for (int n = 0; n < 4; ++n)
        acc[m][n] = __builtin_amdgcn_mfma_f32_16x16x32_bf16(af[m], bf[n], acc[m][n], 0, 0, 0);
  }

  // Epilogue: C row = m-index (e*4+h), col = t. frag: col=lane&15, row=fq*4+reg.
  #pragma unroll
  for (int m = 0; m < 4; ++m)
    #pragma unroll
    for (int n = 0; n < 4; ++n) {
      const int r = r0 + wr * 64 + m * 16 + fq * 4;
      const int t = t0 + wc * 64 + n * 16 + fr;
      #pragma unroll
      for (int g = 0; g < 4; ++g) {
        const int rr = r + g;
        mtT[(size_t)(rr >> 2) * D_ + t * H_ + (rr & 3)] = f2bf(acc[m][n][g]);
      }
    }
}

// ---------------------------------------------------------------------------
// Gather: GT[b][e][j*4+h] = mtT[e][tok[b,j]*4+h]   (bf16, 8B chunks)
// Block = 4 e-rows x all 8 batches; mtT rows stay L1-resident across the
// 8x512 random 8B reads. Tokens cached in LDS. Grid = 768/4 = 192 blocks.
// ---------------------------------------------------------------------------
__global__ __launch_bounds__(256) void gather_k(
    const unsigned short* __restrict__ mtT, const int* __restrict__ x,
    unsigned short* __restrict__ GT) {
  __shared__ int toks[B_ * T_];
  const int tid = threadIdx.x;
  #pragma unroll
  for (int c = 0; c < 16; ++c) toks[c * 256 + tid] = x[c * 256 + tid];
  __syncthreads();

  const int lane = tid & 63, wave = tid >> 6;
  const int e = blockIdx.x * 4 + wave;
  const unsigned short* mrow = mtT + (size_t)e * D_;
  #pragma unroll
  for (int b = 0; b < B_; ++b) {
    unsigned short* grow = GT + ((size_t)b * NE_ + e) * K3;
    const int* tb = toks + b * T_;
    #pragma unroll
    for (int r = 0; r < 8; ++r) {
      const int j = r * 64 + lane;
      const uint2 v = *(const uint2*)(mrow + (size_t)tb[j] * H_);
      *(uint2*)(grow + j * H_) = v;
    }
  }
}

// ---------------------------------------------------------------------------
// Kernel 3 (fast, dense): y[b][i][e] = sum_k att[b,i,k] * GT[b,e,k] + pb[e]
// Per-b GEMM M=512, N=768, K=2048. Same 128x128 global_load_lds structure.
// ---------------------------------------------------------------------------
__global__ __launch_bounds__(256) void gemm3f_k(
    const unsigned short* __restrict__ att,  // [B*T][2048]
    const unsigned short* __restrict__ GT,   // [B][768][2048]
    const float* __restrict__ bias,
    float* __restrict__ y) {
  __shared__ unsigned short As[128 * 32];
  __shared__ unsigned short Bs[128 * 32];
  const int b  = blockIdx.z;
  const int i0 = blockIdx.x * 128;
  const int e0 = blockIdx.y * 128;
  const int tid  = threadIdx.x;
  const int lane = tid & 63, wave = tid >> 6;
  const int wr = wave >> 1, wc = wave & 1;
  const int fr = lane & 15, fq = lane >> 4;
  const int l4 = lane >> 2, lb = lane & 3;

  f32x4 acc[4][4];
  #pragma unroll
  for (int m = 0; m < 4; ++m)
    #pragma unroll
    for (int n = 0; n < 4; ++n) acc[m][n] = (f32x4){0.f, 0.f, 0.f, 0.f};

  const unsigned short* aB = att + (size_t)(b * T_ + i0) * K3;
  const unsigned short* bB = GT + ((size_t)b * NE_ + e0) * K3;

  for (int k0 = 0; k0 < K3; k0 += 32) {
    __syncthreads();
    #pragma unroll
    for (int c = 0; c < 2; ++c) {
      const int ch  = wave * 2 + c;
      const int row = ch * 16 + l4;
      __builtin_amdgcn_global_load_lds(
          (const __attribute__((address_space(1))) void*)
              (aB + (size_t)row * K3 + k0 + lb * 8),
          (__attribute__((address_space(3))) void*)(As + ch * 512),
          16, 0, 0);
      __builtin_amdgcn_global_load_lds(
          (const __attribute__((address_space(1))) void*)
              (bB + (size_t)row * K3 + k0 + lb * 8),
          (__attribute__((address_space(3))) void*)(Bs + ch * 512),
          16, 0, 0);
    }
    __syncthreads();
    bf16x8 af[4], bf[4];
    #pragma unroll
    for (int m = 0; m < 4; ++m)
      af[m] = *(const bf16x8*)&As[(wr * 64 + m * 16 + fr) * 32 + fq * 8];
    #pragma unroll
    for (int n = 0; n < 4; ++n)
      bf[n] = *(const bf16x8*)&Bs[(wc * 64 + n * 16 + fr) * 32 + fq * 8];
    #pragma unroll
    for (int m = 0; m < 4; ++m)
      #pragma unroll
      for (int n = 0; n < 4; ++n)
        acc[m][n] = __builtin_amdgcn_mfma_f32_16x16x32_bf16(af[m], bf[n], acc[m][n], 0, 0, 0);
  }

  #pragma unroll
  for (int m = 0; m < 4; ++m)
    #pragma unroll
    for (int n = 0; n < 4; ++n) {
      const int i = i0 + wr * 64 + m * 16 + fq * 4;
      const int e = e0 + wc * 64 + n * 16 + fr;
      const float be = bias[e];
      #pragma unroll
      for (int g = 0; g < 4; ++g)
        y[(size_t)(b * T_ + i + g) * NE_ + e] = acc[m][n][g] + be;
    }
}

// ---------------------------------------------------------------------------
// Kernel 2: att[b][i][j*4+h] = softmax_j(cooc[t_i, t_j, h]) + eye  (bf16)
// ---------------------------------------------------------------------------
__global__ __launch_bounds__(64) void softmax_k(
    const int* __restrict__ x, const float* __restrict__ cooc,
    unsigned short* __restrict__ att) {
  const int bi = blockIdx.x;
  const int b = bi >> 9, i = bi & (T_ - 1);
  const int lane = threadIdx.x;
  const int ti = x[b * T_ + i];
  const float* crow = cooc + (size_t)ti * D_;

  float w[8][4];
  #pragma unroll
  for (int r = 0; r < 8; ++r) {
    const int j = lane + r * 64;
    const int tj = x[b * T_ + j];
    const float4 v = *(const float4*)(crow + (size_t)tj * H_);
    w[r][0] = v.x; w[r][1] = v.y; w[r][2] = v.z; w[r][3] = v.w;
  }
  float m[4] = {-1e30f, -1e30f, -1e30f, -1e30f};
  #pragma unroll
  for (int r = 0; r < 8; ++r)
    #pragma unroll
    for (int h = 0; h < 4; ++h) m[h] = fmaxf(m[h], w[r][h]);
  #pragma unroll
  for (int off = 32; off > 0; off >>= 1)
    #pragma unroll
    for (int h = 0; h < 4; ++h) m[h] = fmaxf(m[h], __shfl_xor(m[h], off));
  float s[4] = {0.f, 0.f, 0.f, 0.f};
  #pragma unroll
  for (int r = 0; r < 8; ++r)
    #pragma unroll
    for (int h = 0; h < 4; ++h) { w[r][h] = __expf(w[r][h] - m[h]); s[h] += w[r][h]; }
  #pragma unroll
  for (int off = 32; off > 0; off >>= 1)
    #pragma unroll
    for (int h = 0; h < 4; ++h) s[h] += __shfl_xor(s[h], off);
  float inv[4];
  #pragma unroll
  for (int h = 0; h < 4; ++h) inv[h] = 1.f / s[h];

  unsigned short* arow = att + (size_t)(b * T_ + i) * (T_ * H_);
  #pragma unroll
  for (int r = 0; r < 8; ++r) {
    const int j = lane + r * 64;
    const float d = (j == i) ? 1.f : 0.f;
    ushort4 o;
    o.x = f2bf(w[r][0] * inv[0] + d);
    o.y = f2bf(w[r][1] * inv[1] + d);
    o.z = f2bf(w[r][2] * inv[2] + d);
    o.w = f2bf(w[r][3] * inv[3] + d);
    *(ushort4*)(arow + (size_t)j * H_) = o;
  }
}

// ---------------------------------------------------------------------------
// Fallback kernels (round-1 path, used only if ws too small)
// ---------------------------------------------------------------------------
__global__ __launch_bounds__(256) void gemm1_k(
    const float* __restrict__ pw, const float* __restrict__ cooc,
    unsigned short* __restrict__ mtT) {
  __shared__ unsigned short As[128 * 32];
  __shared__ unsigned short Bs[64 * 32];
  const int h  = blockIdx.z;
  const int e0 = blockIdx.x * 128;
  const int t0 = blockIdx.y * 64;
  const int tid  = threadIdx.x;
  const int lane = tid & 63, wave = tid >> 6;
  const int wr = wave >> 1, wc = wave & 1;
  const int fr = lane & 15, fq = lane >> 4;

  f32x4 acc[4][2];
  #pragma unroll
  for (int m = 0; m < 4; ++m)
    #pragma unroll
    for (int n = 0; n < 2; ++n) acc[m][n] = (f32x4){0.f, 0.f, 0.f, 0.f};

  const float* aB = pw + (size_t)e0 * PWROW + (size_t)h * D_;
  const float* bB = cooc + (size_t)t0 * D_;

  for (int k0 = 0; k0 < D_; k0 += 32) {
    __syncthreads();
    #pragma unroll
    for (int c = 0; c < 4; ++c) {
      const int fe = (c * 256 + tid) * 4;
      const int row = fe >> 5, k = fe & 31;
      const float4 v = *(const float4*)(aB + (size_t)row * PWROW + k0 + k);
      ushort4 o; o.x = f2bf(v.x); o.y = f2bf(v.y); o.z = f2bf(v.z); o.w = f2bf(v.w);
      *(ushort4*)&As[fe] = o;
    }
    #pragma unroll
    for (int c = 0; c < 2; ++c) {
      const int fe = (c * 256 + tid) * 4;
      const int row = fe >> 5, k = fe & 31;
      const float4 v = *(const float4*)(bB + (size_t)row * D_ + k0 + k);
      ushort4 o; o.x = f2bf(v.x); o.y = f2bf(v.y); o.z = f2bf(v.z); o.w = f2bf(v.w);
      *(ushort4*)&Bs[fe] = o;
    }
    __syncthreads();
    bf16x8 af[4], bf[2];
    #pragma unroll
    for (int m = 0; m < 4; ++m)
      af[m] = *(const bf16x8*)&As[(wr * 64 + m * 16 + fr) * 32 + fq * 8];
    #pragma unroll
    for (int n = 0; n < 2; ++n)
      bf[n] = *(const bf16x8*)&Bs[(wc * 32 + n * 16 + fr) * 32 + fq * 8];
    #pragma unroll
    for (int m = 0; m < 4; ++m)
      #pragma unroll
      for (int n = 0; n < 2; ++n)
        acc[m][n] = __builtin_amdgcn_mfma_f32_16x16x32_bf16(af[m], bf[n], acc[m][n], 0, 0, 0);
  }

  #pragma unroll
  for (int m = 0; m < 4; ++m)
    #pragma unroll
    for (int n = 0; n < 2; ++n) {
      const int e = e0 + wr * 64 + m * 16 + fq * 4;
      const int t = t0 + wc * 32 + n * 16 + fr;
      #pragma unroll
      for (int g = 0; g < 4; ++g)
        mtT[(size_t)(e + g) * D_ + t * H_ + h] = f2bf(acc[m][n][g]);
    }
}

__global__ __launch_bounds__(256) void gemm3_k(
    const unsigned short* __restrict__ att, const unsigned short* __restrict__ mtT,
    const int* __restrict__ x, const float* __restrict__ bias,
    float* __restrict__ y) {
  __shared__ unsigned short As[64 * 32];
  __shared__ unsigned short Bs[128 * 32];
  const int b  = blockIdx.z;
  const int i0 = blockIdx.x * 64;
  const int e0 = blockIdx.y * 128;
  const int tid  = threadIdx.x;
  const int lane = tid & 63, wave = tid >> 6;
  const int wr = wave >> 1, wc = wave & 1;
  const int fr = lane & 15, fq = lane >> 4;

  f32x4 acc[2][4];
  #pragma unroll
  for (int m = 0; m < 2; ++m)
    #pragma unroll
    for (int n = 0; n < 4; ++n) acc[m][n] = (f32x4){0.f, 0.f, 0.f, 0.f};

  const unsigned short* aB = att + (size_t)(b * T_ + i0) * (T_ * H_);

  for (int ks = 0; ks < 64; ++ks) {
    const int k0 = ks * 32;
    __syncthreads();
    {
      const int fe = tid * 8;
      const int row = fe >> 5, k = fe & 31;
      const uint4 v = *(const uint4*)(aB + (size_t)row * (T_ * H_) + k0 + k);
      *(uint4*)&As[fe] = v;
    }
    #pragma unroll
    for (int c = 0; c < 4; ++c) {
      const int q = c * 256 + tid;
      const int n = q >> 3, j8 = q & 7;
      const int tj = x[b * T_ + ks * 8 + j8];
      const uint2 v = *(const uint2*)(mtT + (size_t)(e0 + n) * D_ + tj * H_);
      *(uint2*)&Bs[n * 32 + j8 * 4] = v;
    }
    __syncthreads();
    bf16x8 af[2], bf[4];
    #pragma unroll
    for (int m = 0; m < 2; ++m)
      af[m] = *(const bf16x8*)&As[(wr * 32 + m * 16 + fr) * 32 + fq * 8];
    #pragma unroll
    for (int n = 0; n < 4; ++n)
      bf[n] = *(const bf16x8*)&Bs[(wc * 64 + n * 16 + fr) * 32 + fq * 8];
    #pragma unroll
    for (int m = 0; m < 2; ++m)
      #pragma unroll
      for (int n = 0; n < 4; ++n)
        acc[m][n] = __builtin_amdgcn_mfma_f32_16x16x32_bf16(af[m], bf[n], acc[m][n], 0, 0, 0);
  }

  #pragma unroll
  for (int m = 0; m < 2; ++m)
    #pragma unroll
    for (int n = 0; n < 4; ++n) {
      const int i = i0 + wr * 32 + m * 16 + fq * 4;
      const int e = e0 + wc * 64 + n * 16 + fr;
      const float be = bias[e];
      #pragma unroll
      for (int g = 0; g < 4; ++g)
        y[(size_t)(b * T_ + i + g) * NE_ + e] = acc[m][n][g] + be;
    }
}

// ---------------------------------------------------------------------------
extern "C" void kernel_launch(void* const* d_in, const int* in_sizes, int n_in,
                              void* d_out, int out_size, void* d_ws, size_t ws_size,
                              hipStream_t stream) {
  const int*   x    = (const int*)d_in[0];
  const float* cooc = (const float*)d_in[1];
  const float* pw   = (const float*)d_in[2];
  const float* pb   = (const float*)d_in[3];
  float* y = (float*)d_out;

  // Fast-path ws layout (ushort elems): [mtT 6291456][Bq 16777216][Aq 25165824]
  // After gemm1f: GT (12582912 elems) aliases Bq; att (8388608) aliases Aq.
  const size_t MTT_E = (size_t)NE_ * D_;          // 6291456
  const size_t BQ_E  = (size_t)V_ * D_;           // 16777216
  const size_t AQ_E  = (size_t)M1 * D_;           // 25165824
  const size_t need_fast = (MTT_E + BQ_E + AQ_E) * 2;  // 96.5 MB

  unsigned short* mtT = (unsigned short*)d_ws;

  if (ws_size >= need_fast) {
    unsigned short* Bq  = mtT + MTT_E;
    unsigned short* Aq  = Bq + BQ_E;
    unsigned short* GT  = Bq;   // alias: valid after gemm1f (25.2 MB <= 33.5 MB)
    unsigned short* att = Aq;   // alias: valid after gemm1f (16.8 MB <= 50.3 MB)
    hipLaunchKernelGGL(cvt_k, dim3(2048), dim3(256), 0, stream,
                       pw, Aq, (int)(AQ_E / 4));
    hipLaunchKernelGGL(cvt_k, dim3(2048), dim3(256), 0, stream,
                       cooc, Bq, (int)(BQ_E / 4));
    hipLaunchKernelGGL(gemm1f_k, dim3(M1 / 128, V_ / 128), dim3(256), 0, stream,
                       Aq, Bq, mtT);
    hipLaunchKernelGGL(softmax_k, dim3(B_ * T_), dim3(64), 0, stream, x, cooc, att);
    hipLaunchKernelGGL(gather_k, dim3(NE_ / 4), dim3(256), 0, stream, mtT, x, GT);
    hipLaunchKernelGGL(gemm3f_k, dim3(T_ / 128, NE_ / 128, B_), dim3(256), 0, stream,
                       att, GT, pb, y);
  } else {
    // Fallback: round-1 path (29.4 MB ws)
    unsigned short* att = mtT + MTT_E;
    hipLaunchKernelGGL(gemm1_k, dim3(NE_ / 128, V_ / 64, H_), dim3(256), 0, stream,
                       pw, cooc, mtT);
    hipLaunchKernelGGL(softmax_k, dim3(B_ * T_), dim3(64), 0, stream, x, cooc, att);
    hipLaunchKernelGGL(gemm3_k, dim3(T_ / 64, NE_ / 128, B_), dim3(256), 0, stream,
                       att, mtT, x, pb, y);
  }
}

// Round 4
// 256.878 us; speedup vs baseline: 3.4456x; 1.0803x over previous
//
#include <hip/hip_runtime.h>
#include <stdint.h>

// Problem constants
#define B_    8
#define T_    512
#define V_    2048
#define H_    4
#define NE_   768
#define D_    8192      // V_*H_  (inner dim of Mt GEMM, and v-row length)
#define PWROW 32768     // V_*H_*H_ (proj_w row length)
#define M1    3072      // NE_*H_  (rows of proj_w viewed as (3072, 8192))
#define K3    2048      // T_*H_   (inner dim of gemm3)

typedef __attribute__((ext_vector_type(8))) short bf16x8;
typedef __attribute__((ext_vector_type(4))) float f32x4;

__device__ __forceinline__ unsigned short f2bf(float f) {
  union { float f; unsigned int u; } c; c.f = f;
  unsigned int u = c.u;
  return (unsigned short)((u + 0x7FFFu + ((u >> 16) & 1u)) >> 16);
}
__device__ __forceinline__ float bf2f(unsigned short s) {
  union { unsigned int u; float f; } c; c.u = ((unsigned int)s) << 16;
  return c.f;
}

// ---------------------------------------------------------------------------
// fp32 -> bf16 elementwise convert (vectorized, grid-stride)
// ---------------------------------------------------------------------------
__global__ __launch_bounds__(256) void cvt_k(
    const float* __restrict__ src, unsigned short* __restrict__ dst, int n4) {
  int i = blockIdx.x * 256 + threadIdx.x;
  const int stride = gridDim.x * 256;
  for (; i < n4; i += stride) {
    const float4 v = ((const float4*)src)[i];
    ushort4 o;
    o.x = f2bf(v.x); o.y = f2bf(v.y); o.z = f2bf(v.z); o.w = f2bf(v.w);
    ((ushort4*)dst)[i] = o;
  }
}

// ---------------------------------------------------------------------------
// Kernel 1: C[m][t] = sum_{k in [z*kk, z*kk+kk)} Aq[m][k] * Bq[t][k]
// m97 structure: 128x128 tile, BK=32, 4 waves, 4x4 acc/wave, global_load_lds
// width-16. Output scattered into P + z*pstride in mtT layout [e][t*4+h].
// Full-K launch: grid z=1, kk=8192, P=mtT. Split-K: grid z=2, kk=4096.
// ---------------------------------------------------------------------------
__global__ __launch_bounds__(256) void gemm1f_k(
    const unsigned short* __restrict__ Aq,   // [3072][8192]
    const unsigned short* __restrict__ Bq,   // [2048][8192]
    unsigned short* __restrict__ P,          // partial/mtT base
    int kk, size_t pstride) {
  __shared__ unsigned short As[128 * 32];
  __shared__ unsigned short Bs[128 * 32];
  const int r0 = blockIdx.x * 128;   // m
  const int t0 = blockIdx.y * 128;   // t
  const int z  = blockIdx.z;
  const int kbeg = z * kk, kend = kbeg + kk;
  const int tid  = threadIdx.x;
  const int lane = tid & 63, wave = tid >> 6;
  const int wr = wave >> 1, wc = wave & 1;
  const int fr = lane & 15, fq = lane >> 4;
  const int l4 = lane >> 2, lb = lane & 3;   // staging: row-in-chunk, 16B slot
  unsigned short* __restrict__ Pz = P + (size_t)z * pstride;

  f32x4 acc[4][4];
  #pragma unroll
  for (int m = 0; m < 4; ++m)
    #pragma unroll
    for (int n = 0; n < 4; ++n) acc[m][n] = (f32x4){0.f, 0.f, 0.f, 0.f};

  for (int k0 = kbeg; k0 < kend; k0 += 32) {
    __syncthreads();
    #pragma unroll
    for (int c = 0; c < 2; ++c) {
      const int ch  = wave * 2 + c;          // 8 chunks of 16 rows each
      const int row = ch * 16 + l4;
      __builtin_amdgcn_global_load_lds(
          (const __attribute__((address_space(1))) void*)
              (Aq + (size_t)(r0 + row) * D_ + k0 + lb * 8),
          (__attribute__((address_space(3))) void*)(As + ch * 512),
          16, 0, 0);
      __builtin_amdgcn_global_load_lds(
          (const __attribute__((address_space(1))) void*)
              (Bq + (size_t)(t0 + row) * D_ + k0 + lb * 8),
          (__attribute__((address_space(3))) void*)(Bs + ch * 512),
          16, 0, 0);
    }
    __syncthreads();
    bf16x8 af[4], bf[4];
    #pragma unroll
    for (int m = 0; m < 4; ++m)
      af[m] = *(const bf16x8*)&As[(wr * 64 + m * 16 + fr) * 32 + fq * 8];
    #pragma unroll
    for (int n = 0; n < 4; ++n)
      bf[n] = *(const bf16x8*)&Bs[(wc * 64 + n * 16 + fr) * 32 + fq * 8];
    #pragma unroll
    for (int m = 0; m < 4; ++m)
      #pragma unroll
      for (int n = 0; n < 4; ++n)
        acc[m][n] = __builtin_amdgcn_mfma_f32_16x16x32_bf16(af[m], bf[n], acc[m][n], 0, 0, 0);
  }

  // Epilogue: C row = m-index (e*4+h), col = t. frag: col=lane&15, row=fq*4+reg.
  #pragma unroll
  for (int m = 0; m < 4; ++m)
    #pragma unroll
    for (int n = 0; n < 4; ++n) {
      const int r = r0 + wr * 64 + m * 16 + fq * 4;
      const int t = t0 + wc * 64 + n * 16 + fr;
      #pragma unroll
      for (int g = 0; g < 4; ++g) {
        const int rr = r + g;
        Pz[(size_t)(rr >> 2) * D_ + t * H_ + (rr & 3)] = f2bf(acc[m][n][g]);
      }
    }
}

// ---------------------------------------------------------------------------
// Split-K reduce: mtT[i] = bf16(P0[i] + P1[i]); mtT region == P0 region
// (same-index in-place RMW, deterministic). 8 ushorts per thread.
// ---------------------------------------------------------------------------
__global__ __launch_bounds__(256) void reduce_k(
    unsigned short* __restrict__ P0, const unsigned short* __restrict__ P1) {
  const size_t i = ((size_t)blockIdx.x * 256 + threadIdx.x) * 8;
  ushort4 a0 = *(const ushort4*)(P0 + i);
  ushort4 a1 = *(const ushort4*)(P0 + i + 4);
  ushort4 b0 = *(const ushort4*)(P1 + i);
  ushort4 b1 = *(const ushort4*)(P1 + i + 4);
  ushort4 o0, o1;
  o0.x = f2bf(bf2f(a0.x) + bf2f(b0.x));
  o0.y = f2bf(bf2f(a0.y) + bf2f(b0.y));
  o0.z = f2bf(bf2f(a0.z) + bf2f(b0.z));
  o0.w = f2bf(bf2f(a0.w) + bf2f(b0.w));
  o1.x = f2bf(bf2f(a1.x) + bf2f(b1.x));
  o1.y = f2bf(bf2f(a1.y) + bf2f(b1.y));
  o1.z = f2bf(bf2f(a1.z) + bf2f(b1.z));
  o1.w = f2bf(bf2f(a1.w) + bf2f(b1.w));
  *(ushort4*)(P0 + i) = o0;
  *(ushort4*)(P0 + i + 4) = o1;
}

// ---------------------------------------------------------------------------
// Gather: GT[b][e][j*4+h] = mtT[e][tok[b,j]*4+h]   (bf16, 8B chunks)
// ---------------------------------------------------------------------------
__global__ __launch_bounds__(256) void gather_k(
    const unsigned short* __restrict__ mtT, const int* __restrict__ x,
    unsigned short* __restrict__ GT) {
  __shared__ int toks[B_ * T_];
  const int tid = threadIdx.x;
  #pragma unroll
  for (int c = 0; c < 16; ++c) toks[c * 256 + tid] = x[c * 256 + tid];
  __syncthreads();

  const int lane = tid & 63, wave = tid >> 6;
  const int e = blockIdx.x * 4 + wave;
  const unsigned short* mrow = mtT + (size_t)e * D_;
  #pragma unroll
  for (int b = 0; b < B_; ++b) {
    unsigned short* grow = GT + ((size_t)b * NE_ + e) * K3;
    const int* tb = toks + b * T_;
    #pragma unroll
    for (int r = 0; r < 8; ++r) {
      const int j = r * 64 + lane;
      const uint2 v = *(const uint2*)(mrow + (size_t)tb[j] * H_);
      *(uint2*)(grow + j * H_) = v;
    }
  }
}

// ---------------------------------------------------------------------------
// Kernel 3 (dense): y[b][i][e] = sum_k att[b,i,k] * GT[b,e,k] + pb[e]
// Per-b GEMM M=512, N=768, K=2048. BM=128, BN=64, BK=32, 4 waves (2x2),
// wave tile 64x32 (acc 4x2). Grid 4x12x8 = 384 blocks.
// ---------------------------------------------------------------------------
__global__ __launch_bounds__(256) void gemm3f_k(
    const unsigned short* __restrict__ att,  // [B*T][2048]
    const unsigned short* __restrict__ GT,   // [B][768][2048]
    const float* __restrict__ bias,
    float* __restrict__ y) {
  __shared__ unsigned short As[128 * 32];
  __shared__ unsigned short Bs[64 * 32];
  const int b  = blockIdx.z;
  const int i0 = blockIdx.x * 128;
  const int e0 = blockIdx.y * 64;
  const int tid  = threadIdx.x;
  const int lane = tid & 63, wave = tid >> 6;
  const int wr = wave >> 1, wc = wave & 1;
  const int fr = lane & 15, fq = lane >> 4;

  f32x4 acc[4][2];
  #pragma unroll
  for (int m = 0; m < 4; ++m)
    #pragma unroll
    for (int n = 0; n < 2; ++n) acc[m][n] = (f32x4){0.f, 0.f, 0.f, 0.f};

  const unsigned short* aB = att + (size_t)(b * T_ + i0) * K3;
  const unsigned short* bB = GT + ((size_t)b * NE_ + e0) * K3;

  for (int k0 = 0; k0 < K3; k0 += 32) {
    __syncthreads();
    // A tile: 128x32 = 512 chunks of 8 elems; rounds 0-1
    #pragma unroll
    for (int rdi = 0; rdi < 2; ++rdi) {
      const int q = rdi * 256 + tid;
      const int row = q >> 2, koff = (q & 3) * 8;
      __builtin_amdgcn_global_load_lds(
          (const __attribute__((address_space(1))) void*)
              (aB + (size_t)row * K3 + k0 + koff),
          (__attribute__((address_space(3))) void*)(As + q * 8),
          16, 0, 0);
    }
    // B tile: 64x32 = 256 chunks; round 2
    {
      const int q = tid;
      const int row = q >> 2, koff = (q & 3) * 8;
      __builtin_amdgcn_global_load_lds(
          (const __attribute__((address_space(1))) void*)
              (bB + (size_t)row * K3 + k0 + koff),
          (__attribute__((address_space(3))) void*)(Bs + q * 8),
          16, 0, 0);
    }
    __syncthreads();
    bf16x8 af[4], bf[2];
    #pragma unroll
    for (int m = 0; m < 4; ++m)
      af[m] = *(const bf16x8*)&As[(wr * 64 + m * 16 + fr) * 32 + fq * 8];
    #pragma unroll
    for (int n = 0; n < 2; ++n)
      bf[n] = *(const bf16x8*)&Bs[(wc * 32 + n * 16 + fr) * 32 + fq * 8];
    #pragma unroll
    for (int m = 0; m < 4; ++m)
      #pragma unroll
      for (int n = 0; n < 2; ++n)
        acc[m][n] = __builtin_amdgcn_mfma_f32_16x16x32_bf16(af[m], bf[n], acc[m][n], 0, 0, 0);
  }

  #pragma unroll
  for (int m = 0; m < 4; ++m)
    #pragma unroll
    for (int n = 0; n < 2; ++n) {
      const int i = i0 + wr * 64 + m * 16 + fq * 4;
      const int e = e0 + wc * 32 + n * 16 + fr;
      const float be = bias[e];
      #pragma unroll
      for (int g = 0; g < 4; ++g)
        y[(size_t)(b * T_ + i + g) * NE_ + e] = acc[m][n][g] + be;
    }
}

// ---------------------------------------------------------------------------
// Kernel 2: att[b][i][j*4+h] = softmax_j(cooc[t_i, t_j, h]) + eye  (bf16)
// ---------------------------------------------------------------------------
__global__ __launch_bounds__(64) void softmax_k(
    const int* __restrict__ x, const float* __restrict__ cooc,
    unsigned short* __restrict__ att) {
  const int bi = blockIdx.x;
  const int b = bi >> 9, i = bi & (T_ - 1);
  const int lane = threadIdx.x;
  const int ti = x[b * T_ + i];
  const float* crow = cooc + (size_t)ti * D_;

  float w[8][4];
  #pragma unroll
  for (int r = 0; r < 8; ++r) {
    const int j = lane + r * 64;
    const int tj = x[b * T_ + j];
    const float4 v = *(const float4*)(crow + (size_t)tj * H_);
    w[r][0] = v.x; w[r][1] = v.y; w[r][2] = v.z; w[r][3] = v.w;
  }
  float m[4] = {-1e30f, -1e30f, -1e30f, -1e30f};
  #pragma unroll
  for (int r = 0; r < 8; ++r)
    #pragma unroll
    for (int h = 0; h < 4; ++h) m[h] = fmaxf(m[h], w[r][h]);
  #pragma unroll
  for (int off = 32; off > 0; off >>= 1)
    #pragma unroll
    for (int h = 0; h < 4; ++h) m[h] = fmaxf(m[h], __shfl_xor(m[h], off));
  float s[4] = {0.f, 0.f, 0.f, 0.f};
  #pragma unroll
  for (int r = 0; r < 8; ++r)
    #pragma unroll
    for (int h = 0; h < 4; ++h) { w[r][h] = __expf(w[r][h] - m[h]); s[h] += w[r][h]; }
  #pragma unroll
  for (int off = 32; off > 0; off >>= 1)
    #pragma unroll
    for (int h = 0; h < 4; ++h) s[h] += __shfl_xor(s[h], off);
  float inv[4];
  #pragma unroll
  for (int h = 0; h < 4; ++h) inv[h] = 1.f / s[h];

  unsigned short* arow = att + (size_t)(b * T_ + i) * (T_ * H_);
  #pragma unroll
  for (int r = 0; r < 8; ++r) {
    const int j = lane + r * 64;
    const float d = (j == i) ? 1.f : 0.f;
    ushort4 o;
    o.x = f2bf(w[r][0] * inv[0] + d);
    o.y = f2bf(w[r][1] * inv[1] + d);
    o.z = f2bf(w[r][2] * inv[2] + d);
    o.w = f2bf(w[r][3] * inv[3] + d);
    *(ushort4*)(arow + (size_t)j * H_) = o;
  }
}

// ---------------------------------------------------------------------------
// Fallback kernels (round-1 path, used only if ws too small)
// ---------------------------------------------------------------------------
__global__ __launch_bounds__(256) void gemm1_k(
    const float* __restrict__ pw, const float* __restrict__ cooc,
    unsigned short* __restrict__ mtT) {
  __shared__ unsigned short As[128 * 32];
  __shared__ unsigned short Bs[64 * 32];
  const int h  = blockIdx.z;
  const int e0 = blockIdx.x * 128;
  const int t0 = blockIdx.y * 64;
  const int tid  = threadIdx.x;
  const int lane = tid & 63, wave = tid >> 6;
  const int wr = wave >> 1, wc = wave & 1;
  const int fr = lane & 15, fq = lane >> 4;

  f32x4 acc[4][2];
  #pragma unroll
  for (int m = 0; m < 4; ++m)
    #pragma unroll
    for (int n = 0; n < 2; ++n) acc[m][n] = (f32x4){0.f, 0.f, 0.f, 0.f};

  const float* aB = pw + (size_t)e0 * PWROW + (size_t)h * D_;
  const float* bB = cooc + (size_t)t0 * D_;

  for (int k0 = 0; k0 < D_; k0 += 32) {
    __syncthreads();
    #pragma unroll
    for (int c = 0; c < 4; ++c) {
      const int fe = (c * 256 + tid) * 4;
      const int row = fe >> 5, k = fe & 31;
      const float4 v = *(const float4*)(aB + (size_t)row * PWROW + k0 + k);
      ushort4 o; o.x = f2bf(v.x); o.y = f2bf(v.y); o.z = f2bf(v.z); o.w = f2bf(v.w);
      *(ushort4*)&As[fe] = o;
    }
    #pragma unroll
    for (int c = 0; c < 2; ++c) {
      const int fe = (c * 256 + tid) * 4;
      const int row = fe >> 5, k = fe & 31;
      const float4 v = *(const float4*)(bB + (size_t)row * D_ + k0 + k);
      ushort4 o; o.x = f2bf(v.x); o.y = f2bf(v.y); o.z = f2bf(v.z); o.w = f2bf(v.w);
      *(ushort4*)&Bs[fe] = o;
    }
    __syncthreads();
    bf16x8 af[4], bf[2];
    #pragma unroll
    for (int m = 0; m < 4; ++m)
      af[m] = *(const bf16x8*)&As[(wr * 64 + m * 16 + fr) * 32 + fq * 8];
    #pragma unroll
    for (int n = 0; n < 2; ++n)
      bf[n] = *(const bf16x8*)&Bs[(wc * 32 + n * 16 + fr) * 32 + fq * 8];
    #pragma unroll
    for (int m = 0; m < 4; ++m)
      #pragma unroll
      for (int n = 0; n < 2; ++n)
        acc[m][n] = __builtin_amdgcn_mfma_f32_16x16x32_bf16(af[m], bf[n], acc[m][n], 0, 0, 0);
  }

  #pragma unroll
  for (int m = 0; m < 4; ++m)
    #pragma unroll
    for (int n = 0; n < 2; ++n) {
      const int e = e0 + wr * 64 + m * 16 + fq * 4;
      const int t = t0 + wc * 32 + n * 16 + fr;
      #pragma unroll
      for (int g = 0; g < 4; ++g)
        mtT[(size_t)(e + g) * D_ + t * H_ + h] = f2bf(acc[m][n][g]);
    }
}

__global__ __launch_bounds__(256) void gemm3_k(
    const unsigned short* __restrict__ att, const unsigned short* __restrict__ mtT,
    const int* __restrict__ x, const float* __restrict__ bias,
    float* __restrict__ y) {
  __shared__ unsigned short As[64 * 32];
  __shared__ unsigned short Bs[128 * 32];
  const int b  = blockIdx.z;
  const int i0 = blockIdx.x * 64;
  const int e0 = blockIdx.y * 128;
  const int tid  = threadIdx.x;
  const int lane = tid & 63, wave = tid >> 6;
  const int wr = wave >> 1, wc = wave & 1;
  const int fr = lane & 15, fq = lane >> 4;

  f32x4 acc[2][4];
  #pragma unroll
  for (int m = 0; m < 2; ++m)
    #pragma unroll
    for (int n = 0; n < 4; ++n) acc[m][n] = (f32x4){0.f, 0.f, 0.f, 0.f};

  const unsigned short* aB = att + (size_t)(b * T_ + i0) * (T_ * H_);

  for (int ks = 0; ks < 64; ++ks) {
    const int k0 = ks * 32;
    __syncthreads();
    {
      const int fe = tid * 8;
      const int row = fe >> 5, k = fe & 31;
      const uint4 v = *(const uint4*)(aB + (size_t)row * (T_ * H_) + k0 + k);
      *(uint4*)&As[fe] = v;
    }
    #pragma unroll
    for (int c = 0; c < 4; ++c) {
      const int q = c * 256 + tid;
      const int n = q >> 3, j8 = q & 7;
      const int tj = x[b * T_ + ks * 8 + j8];
      const uint2 v = *(const uint2*)(mtT + (size_t)(e0 + n) * D_ + tj * H_);
      *(uint2*)&Bs[n * 32 + j8 * 4] = v;
    }
    __syncthreads();
    bf16x8 af[2], bf[4];
    #pragma unroll
    for (int m = 0; m < 2; ++m)
      af[m] = *(const bf16x8*)&As[(wr * 32 + m * 16 + fr) * 32 + fq * 8];
    #pragma unroll
    for (int n = 0; n < 4; ++n)
      bf[n] = *(const bf16x8*)&Bs[(wc * 64 + n * 16 + fr) * 32 + fq * 8];
    #pragma unroll
    for (int m = 0; m < 2; ++m)
      #pragma unroll
      for (int n = 0; n < 4; ++n)
        acc[m][n] = __builtin_amdgcn_mfma_f32_16x16x32_bf16(af[m], bf[n], acc[m][n], 0, 0, 0);
  }

  #pragma unroll
  for (int m = 0; m < 2; ++m)
    #pragma unroll
    for (int n = 0; n < 4; ++n) {
      const int i = i0 + wr * 32 + m * 16 + fq * 4;
      const int e = e0 + wc * 64 + n * 16 + fr;
      const float be = bias[e];
      #pragma unroll
      for (int g = 0; g < 4; ++g)
        y[(size_t)(b * T_ + i + g) * NE_ + e] = acc[m][n][g] + be;
    }
}

// ---------------------------------------------------------------------------
extern "C" void kernel_launch(void* const* d_in, const int* in_sizes, int n_in,
                              void* d_out, int out_size, void* d_ws, size_t ws_size,
                              hipStream_t stream) {
  const int*   x    = (const int*)d_in[0];
  const float* cooc = (const float*)d_in[1];
  const float* pw   = (const float*)d_in[2];
  const float* pb   = (const float*)d_in[3];
  float* y = (float*)d_out;

  const size_t MTT_E = (size_t)NE_ * D_;          // 6291456
  const size_t BQ_E  = (size_t)V_ * D_;           // 16777216
  const size_t AQ_E  = (size_t)M1 * D_;           // 25165824
  const size_t need_mid   = (MTT_E + BQ_E + AQ_E) * 2;            // 96.5 MB
  const size_t need_split = (2 * MTT_E + BQ_E + AQ_E) * 2;        // 109.1 MB

  unsigned short* mtT = (unsigned short*)d_ws;   // == P0

  if (ws_size >= need_split) {
    // [P0/mtT][P1][Bq][Aq]; after gemm1: GT aliases Bq, att aliases Aq.
    unsigned short* P1  = mtT + MTT_E;
    unsigned short* Bq  = P1 + MTT_E;
    unsigned short* Aq  = Bq + BQ_E;
    unsigned short* GT  = Bq;
    unsigned short* att = Aq;
    hipLaunchKernelGGL(cvt_k, dim3(2048), dim3(256), 0, stream,
                       pw, Aq, (int)(AQ_E / 4));
    hipLaunchKernelGGL(cvt_k, dim3(2048), dim3(256), 0, stream,
                       cooc, Bq, (int)(BQ_E / 4));
    hipLaunchKernelGGL(gemm1f_k, dim3(M1 / 128, V_ / 128, 2), dim3(256), 0, stream,
                       Aq, Bq, mtT, D_ / 2, MTT_E);
    hipLaunchKernelGGL(reduce_k, dim3((unsigned)(MTT_E / (256 * 8))), dim3(256), 0,
                       stream, mtT, P1);
    hipLaunchKernelGGL(softmax_k, dim3(B_ * T_), dim3(64), 0, stream, x, cooc, att);
    hipLaunchKernelGGL(gather_k, dim3(NE_ / 4), dim3(256), 0, stream, mtT, x, GT);
    hipLaunchKernelGGL(gemm3f_k, dim3(T_ / 128, NE_ / 64, B_), dim3(256), 0, stream,
                       att, GT, pb, y);
  } else if (ws_size >= need_mid) {
    // Round-3 layout: [mtT][Bq][Aq]; GT aliases Bq, att aliases Aq.
    unsigned short* Bq  = mtT + MTT_E;
    unsigned short* Aq  = Bq + BQ_E;
    unsigned short* GT  = Bq;
    unsigned short* att = Aq;
    hipLaunchKernelGGL(cvt_k, dim3(2048), dim3(256), 0, stream,
                       pw, Aq, (int)(AQ_E / 4));
    hipLaunchKernelGGL(cvt_k, dim3(2048), dim3(256), 0, stream,
                       cooc, Bq, (int)(BQ_E / 4));
    hipLaunchKernelGGL(gemm1f_k, dim3(M1 / 128, V_ / 128, 1), dim3(256), 0, stream,
                       Aq, Bq, mtT, D_, (size_t)0);
    hipLaunchKernelGGL(softmax_k, dim3(B_ * T_), dim3(64), 0, stream, x, cooc, att);
    hipLaunchKernelGGL(gather_k, dim3(NE_ / 4), dim3(256), 0, stream, mtT, x, GT);
    hipLaunchKernelGGL(gemm3f_k, dim3(T_ / 128, NE_ / 64, B_), dim3(256), 0, stream,
                       att, GT, pb, y);
  } else {
    // Fallback: round-1 path (29.4 MB ws)
    unsigned short* att = mtT + MTT_E;
    hipLaunchKernelGGL(gemm1_k, dim3(NE_ / 128, V_ / 64, H_), dim3(256), 0, stream,
                       pw, cooc, mtT);
    hipLaunchKernelGGL(softmax_k, dim3(B_ * T_), dim3(64), 0, stream, x, cooc, att);
    hipLaunchKernelGGL(gemm3_k, dim3(T_ / 64, NE_ / 128, B_), dim3(256), 0, stream,
                       att, mtT, x, pb, y);
  }
}